// Round 1
// baseline (311.555 us; speedup 1.0000x reference)
//
#include <hip/hip_runtime.h>

#define NN 50000
#define NE 800000
#define D 64

// out[node][d] = b_neigh[d] + sum_k feat[node][k] * W_self[d][k]
// h[node][d]   =              sum_k feat[node][k] * W_neigh[k][d]
__global__ __launch_bounds__(256) void gc_matmuls(
    const float* __restrict__ feat, const float* __restrict__ Wn,
    const float* __restrict__ bn, const float* __restrict__ Ws,
    float* __restrict__ out, float* __restrict__ h)
{
    int gid = blockIdx.x * 256 + threadIdx.x;
    int node = gid >> 6;
    int d = gid & 63;
    if (node >= NN) return;
    const float* frow = feat + node * D;
    float accS = bn[d];
    float accH = 0.f;
#pragma unroll
    for (int k = 0; k < D; ++k) {
        float f = frow[k];
        accS += f * Ws[d * D + k];     // row d of W_self, contiguous
        accH += f * Wn[k * D + d];     // column d of W_neigh
    }
    out[node * D + d] = accS;
    h[node * D + d] = accH;
}

// For each edge e: out[dst[e]][d] += ew[e] * h[src[e]][d]   (valid since
// segment_sum commutes with the linear layer applied in gc_matmuls)
__global__ __launch_bounds__(256) void gc_scatter(
    const float* __restrict__ h, const int* __restrict__ src,
    const int* __restrict__ dst, const float* __restrict__ ew,
    float* out)
{
    long long gid = (long long)blockIdx.x * 256 + threadIdx.x;
    int e = (int)(gid >> 6);
    int d = (int)(gid & 63);
    if (e >= NE) return;
    int s = src[e];
    int t = dst[e];
    float w = ew[e];
    atomicAdd(&out[t * D + d], h[s * D + d] * w);
}

extern "C" void kernel_launch(void* const* d_in, const int* in_sizes, int n_in,
                              void* d_out, int out_size, void* d_ws, size_t ws_size,
                              hipStream_t stream) {
    const float* feat = (const float*)d_in[0];
    const int*   src  = (const int*)d_in[1];
    const int*   dst  = (const int*)d_in[2];
    const float* ew   = (const float*)d_in[3];
    const float* Wn   = (const float*)d_in[4];
    const float* bn   = (const float*)d_in[5];
    const float* Ws   = (const float*)d_in[6];
    float* out = (float*)d_out;
    float* h   = (float*)d_ws;   // NN*D floats = 12.8 MB

    {
        int total = NN * D;
        int blocks = (total + 255) / 256;
        gc_matmuls<<<blocks, 256, 0, stream>>>(feat, Wn, bn, Ws, out, h);
    }
    {
        long long total = (long long)NE * D;
        int blocks = (int)((total + 255) / 256);
        gc_scatter<<<blocks, 256, 0, stream>>>(h, src, dst, ew, out);
    }
}

// Round 3
// 191.904 us; speedup vs baseline: 1.6235x; 1.6235x over previous
//
#include <hip/hip_runtime.h>

#define NN 50000
#define NE 800000
#define D 64
#define SCAN_B ((NN + 255) / 256)   // 196 blocks

// ---- workspace layout (bytes, 1024-aligned) ----
constexpr size_t alignup(size_t x) { return (x + 1023) & ~size_t(1023); }
constexpr size_t OFF_AGG    = 0;                                          // NN*D f32 = 12.8 MB
constexpr size_t OFF_COUNTS = alignup(OFF_AGG + (size_t)NN * D * 4);      // NN i32
constexpr size_t OFF_RS     = alignup(OFF_COUNTS + (size_t)NN * 4);       // NN+1 i32
constexpr size_t OFF_CUR    = alignup(OFF_RS + (size_t)(NN + 1) * 4);     // NN i32
constexpr size_t OFF_BSUM   = alignup(OFF_CUR + (size_t)NN * 4);          // 256 i32
constexpr size_t OFF_BSUMX  = alignup(OFF_BSUM + 1024);                   // 256 i32
constexpr size_t OFF_EM     = alignup(OFF_BSUMX + 1024);                  // NE int2 = 6.4 MB
// total ~19.8 MB

// K0: zero counters
__global__ __launch_bounds__(256) void gc_init(int* counts, int* cur, int* rs) {
    int g = blockIdx.x * 256 + threadIdx.x;
    if (g < NN) { counts[g] = 0; cur[g] = 0; }
    if (g == 0) rs[0] = 0;
}

// K1: histogram of dst
__global__ __launch_bounds__(256) void gc_hist(const int* __restrict__ dst, int* counts) {
    int e = blockIdx.x * 256 + threadIdx.x;
    if (e < NE) atomicAdd(&counts[dst[e]], 1);
}

// K2a: per-block inclusive scan; rs[g+1] = partial, bsum[b] = block total
__global__ __launch_bounds__(256) void gc_scan_a(const int* __restrict__ counts,
                                                 int* rs, int* bsum) {
    __shared__ int sh[256];
    int t = threadIdx.x;
    int g = blockIdx.x * 256 + t;
    int v = (g < NN) ? counts[g] : 0;
    sh[t] = v;
    __syncthreads();
    for (int o = 1; o < 256; o <<= 1) {
        int x = (t >= o) ? sh[t - o] : 0;
        __syncthreads();
        sh[t] += x;
        __syncthreads();
    }
    if (g < NN) rs[g + 1] = sh[t];
    if (t == 255) bsum[blockIdx.x] = sh[t];
}

// K2b: exclusive scan of block sums (single block)
__global__ __launch_bounds__(256) void gc_scan_b(const int* __restrict__ bsum, int* bsumX) {
    __shared__ int sh[256];
    int t = threadIdx.x;
    int v = (t < SCAN_B) ? bsum[t] : 0;
    sh[t] = v;
    __syncthreads();
    for (int o = 1; o < 256; o <<= 1) {
        int x = (t >= o) ? sh[t - o] : 0;
        __syncthreads();
        sh[t] += x;
        __syncthreads();
    }
    bsumX[t] = sh[t] - v;   // exclusive
}

// K2c: add block offsets
__global__ __launch_bounds__(256) void gc_scan_c(int* rs, const int* __restrict__ bsumX) {
    int g = blockIdx.x * 256 + threadIdx.x;
    if (g < NN) rs[g + 1] += bsumX[blockIdx.x];
}

// K3: reorder edges into CSR slots: em[pos] = {src, ew}
__global__ __launch_bounds__(256) void gc_reorder(const int* __restrict__ src,
                                                  const int* __restrict__ dst,
                                                  const float* __restrict__ ew,
                                                  const int* __restrict__ rs,
                                                  int* cur, int2* em) {
    int e = blockIdx.x * 256 + threadIdx.x;
    if (e >= NE) return;
    int t = dst[e];
    int pos = rs[t] + atomicAdd(&cur[t], 1);
    em[pos] = make_int2(src[e], __float_as_int(ew[e]));
}

// K4: gather — one wave per dst node, lane d accumulates channel d in register
__global__ __launch_bounds__(256) void gc_gather(const float* __restrict__ feat,
                                                 const int* __restrict__ rs,
                                                 const int2* __restrict__ em,
                                                 float* __restrict__ agg) {
    int wid = threadIdx.x >> 6;
    int d = threadIdx.x & 63;
    int n = blockIdx.x * 4 + wid;
    if (n >= NN) return;
    int beg = __builtin_amdgcn_readfirstlane(rs[n]);
    int end = __builtin_amdgcn_readfirstlane(rs[n + 1]);
    float acc = 0.f;
    for (int e = beg; e < end; ++e) {
        int2 v = em[e];
        acc = fmaf(__int_as_float(v.y), feat[(size_t)v.x * D + d], acc);
    }
    agg[(size_t)n * D + d] = acc;
}

// K5: out[n][d] = bn[d] + sum_k agg[n][k]*Wn[k][d] + sum_k feat[n][k]*Ws[d][k]
// Wn and Ws^T staged interleaved in LDS: WB[2*(k*64+d)] = Wn[k][d], +1 = Ws[d][k]
__global__ __launch_bounds__(256) void gc_out(const float* __restrict__ feat,
                                              const float* __restrict__ agg,
                                              const float* __restrict__ Wn,
                                              const float* __restrict__ Ws,
                                              const float* __restrict__ bn,
                                              float* __restrict__ out) {
    __shared__ float WB[D * D * 2];   // 32 KB
    for (int i = threadIdx.x; i < D * D; i += 256) {
        int k = i >> 6, d = i & 63;
        WB[2 * i]     = Wn[i];            // Wn[k][d], coalesced
        WB[2 * i + 1] = Ws[d * D + k];    // Ws row d, k consecutive -> coalesced
    }
    __syncthreads();
    int d = threadIdx.x & 63;
    float bias = bn[d];
    int wave = blockIdx.x * 4 + (threadIdx.x >> 6);
    int nwave = gridDim.x * 4;
    for (int n0 = wave * 2; n0 < NN; n0 += nwave * 2) {
        int n0u = __builtin_amdgcn_readfirstlane(n0);
        const float* f0 = feat + (size_t)n0u * D;
        const float* a0 = agg + (size_t)n0u * D;
        bool two = (n0u + 1 < NN);
        const float* f1 = f0 + (two ? D : 0);
        const float* a1 = a0 + (two ? D : 0);
        float acc0 = bias, acc1 = bias;
#pragma unroll 8
        for (int k = 0; k < D; ++k) {
            float2 w = *(const float2*)&WB[2 * (k * D + d)];
            acc0 = fmaf(a0[k], w.x, acc0);
            acc0 = fmaf(f0[k], w.y, acc0);
            acc1 = fmaf(a1[k], w.x, acc1);
            acc1 = fmaf(f1[k], w.y, acc1);
        }
        out[(size_t)n0u * D + d] = acc0;
        if (two) out[(size_t)(n0u + 1) * D + d] = acc1;
    }
}

extern "C" void kernel_launch(void* const* d_in, const int* in_sizes, int n_in,
                              void* d_out, int out_size, void* d_ws, size_t ws_size,
                              hipStream_t stream) {
    const float* feat = (const float*)d_in[0];
    const int*   src  = (const int*)d_in[1];
    const int*   dst  = (const int*)d_in[2];
    const float* ew   = (const float*)d_in[3];
    const float* Wn   = (const float*)d_in[4];
    const float* bn   = (const float*)d_in[5];
    const float* Ws   = (const float*)d_in[6];
    float* out = (float*)d_out;

    char* ws = (char*)d_ws;
    float* agg   = (float*)(ws + OFF_AGG);
    int* counts  = (int*)(ws + OFF_COUNTS);
    int* rs      = (int*)(ws + OFF_RS);
    int* cur     = (int*)(ws + OFF_CUR);
    int* bsum    = (int*)(ws + OFF_BSUM);
    int* bsumX   = (int*)(ws + OFF_BSUMX);
    int2* em     = (int2*)(ws + OFF_EM);

    int nb_n = (NN + 255) / 256;     // 196
    int nb_e = (NE + 255) / 256;     // 3125

    gc_init<<<nb_n, 256, 0, stream>>>(counts, cur, rs);
    gc_hist<<<nb_e, 256, 0, stream>>>(dst, counts);
    gc_scan_a<<<SCAN_B, 256, 0, stream>>>(counts, rs, bsum);
    gc_scan_b<<<1, 256, 0, stream>>>(bsum, bsumX);
    gc_scan_c<<<SCAN_B, 256, 0, stream>>>(rs, bsumX);
    gc_reorder<<<nb_e, 256, 0, stream>>>(src, dst, ew, rs, cur, em);
    gc_gather<<<(NN + 3) / 4, 256, 0, stream>>>(feat, rs, em, agg);
    gc_out<<<1024, 256, 0, stream>>>(feat, agg, Wn, Ws, bn, out);
}